// Round 1
// baseline (157.764 us; speedup 1.0000x reference)
//
#include <hip/hip_runtime.h>
#include <math.h>

#define IMG_H 512
#define IMG_W 512
#define NB 9

// r16: split each 8x8 cell across a lane PAIR (lane ^ 32): half 0 = rows 0-3,
// half 1 = rows 4-7. Grid 2048 blocks x 4 waves = 8192 waves = 100% of the
// 256CU x 32-slot capacity (r15 decomposition capped occupancy at 50%:
// 4096 waves, measured 44.8%, VALUBusy 29% -> latency-bound).
// Pair reduction: 9x __shfl_xor(32); half 0 stores bins 0-4, half 1 bins 5-8.
// Numerics FROZEN from r14 per-pixel (f32 pairwise-9 conv, sector fast path,
// CR-atan2 boundary window, razor hedge). Only deltas, all argued exact or
// sub-ulp:
//  - cell sum = (rows0-3) + (rows4-7) reassociation (~1 ulp of cell sum).
//  - flag via min3: OR(a_i*KW<E) == min(a_i)*KW<E (terms >=0, rounding
//    monotone) — bit-identical decision.
//  - accumulate loop over k<8 only; fast-path bin is provably in [0,7];
//    slow-path bin==8 adds directly then contributes +0.0f (exact).
__global__ __launch_bounds__(256, 8) void hog_kernel(const float* __restrict__ x,
                                                     float* __restrict__ out) {
#pragma clang fp contract(off)
    const int tid  = threadIdx.x;
    const int w    = tid >> 6;          // wave in block 0..3
    const int lane = tid & 63;
    const int cl   = lane & 31;         // cell within wave-half
    const int half = lane >> 5;         // 0: rows 0-3, 1: rows 4-7

    const int cx = ((w & 1) << 5) | cl;             // cell col 0..63
    const int cy = (blockIdx.x << 1) | (w >> 1);    // cell row 0..63
    const int n  = blockIdx.y;                      // image 0..63

    const float* img = x + (size_t)n * (IMG_H * IMG_W);
    const int x0 = cx << 3;
    const int y0 = (cy << 3) + (half << 2);         // first compute row

    float a[10], b[10], c[10];
    float acc[NB];
#pragma unroll
    for (int k = 0; k < NB; ++k) acc[k] = 0.0f;

    auto load_row = [&](float* r, int y) {
        if (y < 0 || y >= IMG_H) {
#pragma unroll
            for (int i = 0; i < 10; ++i) r[i] = 0.0f;
            return;
        }
        const float* row = img + (size_t)y * IMG_W;
        const float4 p0 = *(const float4*)(row + x0);
        const float4 p1 = *(const float4*)(row + x0 + 4);
        r[1] = p0.x; r[2] = p0.y; r[3] = p0.z; r[4] = p0.w;
        r[5] = p1.x; r[6] = p1.y; r[7] = p1.z; r[8] = p1.w;
        r[0] = (x0 == 0)         ? 0.0f : row[x0 - 1];
        r[9] = (x0 + 8 >= IMG_W) ? 0.0f : row[x0 + 8];
    };

    load_row(a, y0 - 1);
    load_row(b, y0);

    const float PI_F = 3.14159274101257324f;   // float32(pi)
    const float T1F  = 0.41421356237309503f;   // tan(pi/8) -> f32
    const float T3F  = 2.41421356237309503f;   // tan(3pi/8) -> f32
    const float KPI  = 2.54647909f;            // 8/pi
    const float EPS  = 5e-5f;                  // boundary window in t-units

#pragma unroll
    for (int ry = 0; ry < 4; ++ry) {
        load_row(c, y0 + ry + 1);

#pragma unroll
        for (int j = 0; j < 8; ++j) {
            const float A0 = a[j], A1 = a[j + 1], A2 = a[j + 2];
            const float B0 = b[j], B2 = b[j + 2];
            const float C0 = c[j], C1 = c[j + 1], C2 = c[j + 2];

            // numpy pairwise-9 association (one f32 rounding per add):
            const float gx = ((-A0 + (A2 - 2.0f * B0)) + (2.0f * B2 - C0)) + C2;
            const float gy = (((-A0 - 2.0f * A1) + (-A2)) + (C0 + 2.0f * C1)) + C2;

            const float u = fabsf(gx);
            const float W = fabsf(gy);
            const float q = u * u + W * W;
            const float mag = sqrtf(q);

            // sector fast path: boundaries u/W in {tan(pi/8), 1, tan(3pi/8)}
            const float b1 = W * T1F;
            const float b3 = W * T3F;
            const int cnt = (int)(u > b1) + (int)(u > b3) + (int)(u > W);
            int bin = (gy > 0.0f) ? cnt : 7 - cnt;
            float wA = mag;

            // boundary window, min3 form (== r14's OR form bit-identically:
            // all terms >=0, rounding monotone => min before the one product)
            const float KW = KPI * W;
            const float E  = EPS * q;
            const float md = fminf(fminf(fabsf(u - b1), fabsf(u - b3)),
                                   fminf(fabsf(u - W), u));

            if (md * KW < E) {
                // faithful r14 chain: CR f32 atan2 (via f64), CR f32 div
                const float angf = (float)atan2((double)u, (double)gy);
                const float tc = (float)((double)angf / (double)PI_F) * 8.0f;
                int bc = (int)tc;
                bin = bc > 8 ? 8 : bc;
                const float tn = roundf(tc);
                const int B = (int)tn;
                if (B >= 1 && B <= 8 && fabsf(tc - tn) < 4e-6f &&
                    mag <= 1.05f) {
                    // razor hedge: 50/50 split across {B-1, B}
                    const float hw = 0.5f * mag;
                    bin = B - 1; wA = hw;
#pragma unroll
                    for (int k = 0; k < NB; ++k)
                        acc[k] += (k == B) ? hw : 0.0f;
                }
                if (bin == 8) {         // slow-path-only case; loop below
                    acc[8] += wA;       // then adds exact +0.0f to acc[0]
                    wA = 0.0f; bin = 0;
                }
            }

#pragma unroll
            for (int k = 0; k < 8; ++k)
                acc[k] += (bin == k) ? wA : 0.0f;
        }

#pragma unroll
        for (int i = 0; i < 10; ++i) { a[i] = b[i]; b[i] = c[i]; }
    }

    // pair reduction: partner lane (^32) holds the other 4 rows of this cell.
    // Both lanes compute accL+accH (commutative, identical rounding).
#pragma unroll
    for (int k = 0; k < NB; ++k)
        acc[k] += __shfl_xor(acc[k], 32, 64);

    // out layout: [n, bin, cy, cx]; split the 9 stores across the pair
    float* o = out + (size_t)n * (NB * 64 * 64) + (size_t)cy * 64 + cx;
    if (half == 0) {
#pragma unroll
        for (int k = 0; k < 5; ++k) o[(size_t)k * 4096] = acc[k];
    } else {
#pragma unroll
        for (int k = 5; k < NB; ++k) o[(size_t)k * 4096] = acc[k];
    }
}

extern "C" void kernel_launch(void* const* d_in, const int* in_sizes, int n_in,
                              void* d_out, int out_size, void* d_ws, size_t ws_size,
                              hipStream_t stream) {
    const float* x = (const float*)d_in[0];
    float* out = (float*)d_out;
    hog_kernel<<<dim3(32, 64, 1), dim3(256, 1, 1), 0, stream>>>(x, out);
}

// Round 2
// 136.552 us; speedup vs baseline: 1.1553x; 1.1553x over previous
//
#include <hip/hip_runtime.h>
#include <math.h>

#define IMG_H 512
#define IMG_W 512
#define NB 9

// r17: r16 pair-split decomposition, spill fixed.
// r16 post-mortem: __launch_bounds__(256,8) capped VGPR at 64 < ~60-reg
// working set + temps -> compiler demoted the rolling-window arrays to
// scratch (VGPR_Count 32, WRITE_SIZE 9.2->116 MB, FETCH 41.6->125 MB,
// harness 157 us vs rocprof 82 us: scratch traffic + per-launch scratch
// overhead). Decomposition itself was right: occupancy 44.8->69.8.
// Fix: __launch_bounds__(256,6) -> 84-VGPR cap, demand ~60 fits, 6
// waves/SIMD (75% ceiling ~= measured 69.8 residency) with ZERO scratch.
// Numerics FROZEN from r14 per-pixel (f32 pairwise-9 conv, sector fast
// path, CR-atan2 boundary window, razor hedge); r16 deltas kept:
//  - cell sum = (rows0-3) + (rows4-7) reassociation (~1 ulp of cell sum).
//  - flag via min3: OR(a_i*KW<E) == min(a_i)*KW<E — bit-identical.
//  - accumulate loop k<8; slow-path bin==8 added directly (exact +0.0f).
__global__ __launch_bounds__(256, 6) void hog_kernel(const float* __restrict__ x,
                                                     float* __restrict__ out) {
#pragma clang fp contract(off)
    const int tid  = threadIdx.x;
    const int w    = tid >> 6;          // wave in block 0..3
    const int lane = tid & 63;
    const int cl   = lane & 31;         // cell within wave-half
    const int half = lane >> 5;         // 0: rows 0-3, 1: rows 4-7

    const int cx = ((w & 1) << 5) | cl;             // cell col 0..63
    const int cy = (blockIdx.x << 1) | (w >> 1);    // cell row 0..63
    const int n  = blockIdx.y;                      // image 0..63

    const float* img = x + (size_t)n * (IMG_H * IMG_W);
    const int x0 = cx << 3;
    const int y0 = (cy << 3) + (half << 2);         // first compute row

    float a[10], b[10], c[10];
    float acc[NB];
#pragma unroll
    for (int k = 0; k < NB; ++k) acc[k] = 0.0f;

    auto load_row = [&](float* r, int y) {
        if (y < 0 || y >= IMG_H) {
#pragma unroll
            for (int i = 0; i < 10; ++i) r[i] = 0.0f;
            return;
        }
        const float* row = img + (size_t)y * IMG_W;
        const float4 p0 = *(const float4*)(row + x0);
        const float4 p1 = *(const float4*)(row + x0 + 4);
        r[1] = p0.x; r[2] = p0.y; r[3] = p0.z; r[4] = p0.w;
        r[5] = p1.x; r[6] = p1.y; r[7] = p1.z; r[8] = p1.w;
        r[0] = (x0 == 0)         ? 0.0f : row[x0 - 1];
        r[9] = (x0 + 8 >= IMG_W) ? 0.0f : row[x0 + 8];
    };

    load_row(a, y0 - 1);
    load_row(b, y0);

    const float PI_F = 3.14159274101257324f;   // float32(pi)
    const float T1F  = 0.41421356237309503f;   // tan(pi/8) -> f32
    const float T3F  = 2.41421356237309503f;   // tan(3pi/8) -> f32
    const float KPI  = 2.54647909f;            // 8/pi
    const float EPS  = 5e-5f;                  // boundary window in t-units

#pragma unroll
    for (int ry = 0; ry < 4; ++ry) {
        load_row(c, y0 + ry + 1);

#pragma unroll
        for (int j = 0; j < 8; ++j) {
            const float A0 = a[j], A1 = a[j + 1], A2 = a[j + 2];
            const float B0 = b[j], B2 = b[j + 2];
            const float C0 = c[j], C1 = c[j + 1], C2 = c[j + 2];

            // numpy pairwise-9 association (one f32 rounding per add):
            const float gx = ((-A0 + (A2 - 2.0f * B0)) + (2.0f * B2 - C0)) + C2;
            const float gy = (((-A0 - 2.0f * A1) + (-A2)) + (C0 + 2.0f * C1)) + C2;

            const float u = fabsf(gx);
            const float W = fabsf(gy);
            const float q = u * u + W * W;
            const float mag = sqrtf(q);

            // sector fast path: boundaries u/W in {tan(pi/8), 1, tan(3pi/8)}
            const float b1 = W * T1F;
            const float b3 = W * T3F;
            const int cnt = (int)(u > b1) + (int)(u > b3) + (int)(u > W);
            int bin = (gy > 0.0f) ? cnt : 7 - cnt;
            float wA = mag;

            // boundary window, min3 form (== r14's OR form bit-identically:
            // all terms >=0, rounding monotone => min before the one product)
            const float KW = KPI * W;
            const float E  = EPS * q;
            const float md = fminf(fminf(fabsf(u - b1), fabsf(u - b3)),
                                   fminf(fabsf(u - W), u));

            if (md * KW < E) {
                // faithful r14 chain: CR f32 atan2 (via f64), CR f32 div
                const float angf = (float)atan2((double)u, (double)gy);
                const float tc = (float)((double)angf / (double)PI_F) * 8.0f;
                int bc = (int)tc;
                bin = bc > 8 ? 8 : bc;
                const float tn = roundf(tc);
                const int B = (int)tn;
                if (B >= 1 && B <= 8 && fabsf(tc - tn) < 4e-6f &&
                    mag <= 1.05f) {
                    // razor hedge: 50/50 split across {B-1, B}
                    const float hw = 0.5f * mag;
                    bin = B - 1; wA = hw;
#pragma unroll
                    for (int k = 0; k < NB; ++k)
                        acc[k] += (k == B) ? hw : 0.0f;
                }
                if (bin == 8) {         // slow-path-only case; loop below
                    acc[8] += wA;       // then adds exact +0.0f to acc[0]
                    wA = 0.0f; bin = 0;
                }
            }

#pragma unroll
            for (int k = 0; k < 8; ++k)
                acc[k] += (bin == k) ? wA : 0.0f;
        }

#pragma unroll
        for (int i = 0; i < 10; ++i) { a[i] = b[i]; b[i] = c[i]; }
    }

    // pair reduction: partner lane (^32) holds the other 4 rows of this cell.
    // Both lanes compute accL+accH (commutative, identical rounding).
#pragma unroll
    for (int k = 0; k < NB; ++k)
        acc[k] += __shfl_xor(acc[k], 32, 64);

    // out layout: [n, bin, cy, cx]; split the 9 stores across the pair
    float* o = out + (size_t)n * (NB * 64 * 64) + (size_t)cy * 64 + cx;
    if (half == 0) {
#pragma unroll
        for (int k = 0; k < 5; ++k) o[(size_t)k * 4096] = acc[k];
    } else {
#pragma unroll
        for (int k = 5; k < NB; ++k) o[(size_t)k * 4096] = acc[k];
    }
}

extern "C" void kernel_launch(void* const* d_in, const int* in_sizes, int n_in,
                              void* d_out, int out_size, void* d_ws, size_t ws_size,
                              hipStream_t stream) {
    const float* x = (const float*)d_in[0];
    float* out = (float*)d_out;
    hog_kernel<<<dim3(32, 64, 1), dim3(256, 1, 1), 0, stream>>>(x, out);
}

// Round 3
// 119.436 us; speedup vs baseline: 1.3209x; 1.1433x over previous
//
#include <hip/hip_runtime.h>
#include <math.h>

#define IMG_H 512
#define IMG_W 512
#define NB 9

// r18: r16/r17 pair-split decomposition; spill fixed by returning to the
// ONLY launch-bounds config with proven no-spill codegen.
// r17 post-mortem: (256,6) caps VGPR at 80; allocator demand for this
// 32x-unrolled body (inlined f64 atan2 cold path in each copy) is >80,
// and the compiler demoted the window/acc arrays to scratch (VGPR_Count
// 40, WRITE 48.7MB vs 9.2MB output, occupancy stuck 44%, harness 136us
// vs dispatch 66us from scratch overhead).
// r15 evidence: (256,4) -> 128-VGPR budget -> VGPR=60, WRITE exactly
// 9.2MB (zero scratch). launch_bounds is a MINIMUM waves/EU: it does not
// cap residency. At VGPR<=64 the HW runs 8 waves/SIMD, and this grid
// supplies 8192 waves = 100% of slots -> r16 parallelism + r15 codegen.
// Numerics FROZEN from r14 per-pixel (f32 pairwise-9 conv, sector fast
// path, CR-atan2 boundary window, razor hedge); r16 deltas kept:
//  - cell sum = (rows0-3) + (rows4-7) reassociation (~1 ulp of cell sum).
//  - flag via min3: OR(a_i*KW<E) == min(a_i)*KW<E — bit-identical.
//  - accumulate loop k<8; slow-path bin==8 added directly (exact +0.0f).
__global__ __launch_bounds__(256, 4) void hog_kernel(const float* __restrict__ x,
                                                     float* __restrict__ out) {
#pragma clang fp contract(off)
    const int tid  = threadIdx.x;
    const int w    = tid >> 6;          // wave in block 0..3
    const int lane = tid & 63;
    const int cl   = lane & 31;         // cell within wave-half
    const int half = lane >> 5;         // 0: rows 0-3, 1: rows 4-7

    const int cx = ((w & 1) << 5) | cl;             // cell col 0..63
    const int cy = (blockIdx.x << 1) | (w >> 1);    // cell row 0..63
    const int n  = blockIdx.y;                      // image 0..63

    const float* img = x + (size_t)n * (IMG_H * IMG_W);
    const int x0 = cx << 3;
    const int y0 = (cy << 3) + (half << 2);         // first compute row

    float a[10], b[10], c[10];
    float acc[NB];
#pragma unroll
    for (int k = 0; k < NB; ++k) acc[k] = 0.0f;

    auto load_row = [&](float* r, int y) {
        if (y < 0 || y >= IMG_H) {
#pragma unroll
            for (int i = 0; i < 10; ++i) r[i] = 0.0f;
            return;
        }
        const float* row = img + (size_t)y * IMG_W;
        const float4 p0 = *(const float4*)(row + x0);
        const float4 p1 = *(const float4*)(row + x0 + 4);
        r[1] = p0.x; r[2] = p0.y; r[3] = p0.z; r[4] = p0.w;
        r[5] = p1.x; r[6] = p1.y; r[7] = p1.z; r[8] = p1.w;
        r[0] = (x0 == 0)         ? 0.0f : row[x0 - 1];
        r[9] = (x0 + 8 >= IMG_W) ? 0.0f : row[x0 + 8];
    };

    load_row(a, y0 - 1);
    load_row(b, y0);

    const float PI_F = 3.14159274101257324f;   // float32(pi)
    const float T1F  = 0.41421356237309503f;   // tan(pi/8) -> f32
    const float T3F  = 2.41421356237309503f;   // tan(3pi/8) -> f32
    const float KPI  = 2.54647909f;            // 8/pi
    const float EPS  = 5e-5f;                  // boundary window in t-units

#pragma unroll
    for (int ry = 0; ry < 4; ++ry) {
        load_row(c, y0 + ry + 1);

#pragma unroll
        for (int j = 0; j < 8; ++j) {
            const float A0 = a[j], A1 = a[j + 1], A2 = a[j + 2];
            const float B0 = b[j], B2 = b[j + 2];
            const float C0 = c[j], C1 = c[j + 1], C2 = c[j + 2];

            // numpy pairwise-9 association (one f32 rounding per add):
            const float gx = ((-A0 + (A2 - 2.0f * B0)) + (2.0f * B2 - C0)) + C2;
            const float gy = (((-A0 - 2.0f * A1) + (-A2)) + (C0 + 2.0f * C1)) + C2;

            const float u = fabsf(gx);
            const float W = fabsf(gy);
            const float q = u * u + W * W;
            const float mag = sqrtf(q);

            // sector fast path: boundaries u/W in {tan(pi/8), 1, tan(3pi/8)}
            const float b1 = W * T1F;
            const float b3 = W * T3F;
            const int cnt = (int)(u > b1) + (int)(u > b3) + (int)(u > W);
            int bin = (gy > 0.0f) ? cnt : 7 - cnt;
            float wA = mag;

            // boundary window, min3 form (== r14's OR form bit-identically:
            // all terms >=0, rounding monotone => min before the one product)
            const float KW = KPI * W;
            const float E  = EPS * q;
            const float md = fminf(fminf(fabsf(u - b1), fabsf(u - b3)),
                                   fminf(fabsf(u - W), u));

            if (md * KW < E) {
                // faithful r14 chain: CR f32 atan2 (via f64), CR f32 div
                const float angf = (float)atan2((double)u, (double)gy);
                const float tc = (float)((double)angf / (double)PI_F) * 8.0f;
                int bc = (int)tc;
                bin = bc > 8 ? 8 : bc;
                const float tn = roundf(tc);
                const int B = (int)tn;
                if (B >= 1 && B <= 8 && fabsf(tc - tn) < 4e-6f &&
                    mag <= 1.05f) {
                    // razor hedge: 50/50 split across {B-1, B}
                    const float hw = 0.5f * mag;
                    bin = B - 1; wA = hw;
#pragma unroll
                    for (int k = 0; k < NB; ++k)
                        acc[k] += (k == B) ? hw : 0.0f;
                }
                if (bin == 8) {         // slow-path-only case; loop below
                    acc[8] += wA;       // then adds exact +0.0f to acc[0]
                    wA = 0.0f; bin = 0;
                }
            }

#pragma unroll
            for (int k = 0; k < 8; ++k)
                acc[k] += (bin == k) ? wA : 0.0f;
        }

#pragma unroll
        for (int i = 0; i < 10; ++i) { a[i] = b[i]; b[i] = c[i]; }
    }

    // pair reduction: partner lane (^32) holds the other 4 rows of this cell.
    // Both lanes compute accL+accH (commutative, identical rounding).
#pragma unroll
    for (int k = 0; k < NB; ++k)
        acc[k] += __shfl_xor(acc[k], 32, 64);

    // out layout: [n, bin, cy, cx]; split the 9 stores across the pair
    float* o = out + (size_t)n * (NB * 64 * 64) + (size_t)cy * 64 + cx;
    if (half == 0) {
#pragma unroll
        for (int k = 0; k < 5; ++k) o[(size_t)k * 4096] = acc[k];
    } else {
#pragma unroll
        for (int k = 5; k < NB; ++k) o[(size_t)k * 4096] = acc[k];
    }
}

extern "C" void kernel_launch(void* const* d_in, const int* in_sizes, int n_in,
                              void* d_out, int out_size, void* d_ws, size_t ws_size,
                              hipStream_t stream) {
    const float* x = (const float*)d_in[0];
    float* out = (float*)d_out;
    hog_kernel<<<dim3(32, 64, 1), dim3(256, 1, 1), 0, stream>>>(x, out);
}

// Round 4
// 119.105 us; speedup vs baseline: 1.3246x; 1.0028x over previous
//
#include <hip/hip_runtime.h>
#include <math.h>

#define IMG_H 512
#define IMG_W 512
#define NB 9

// r19: 4 threads/cell (4x4 sub-tiles), all-rows-preloaded, cascade accumulate.
// r18 post-mortem: spill fixed (WRITE exactly 9.2MB, VGPR 52, dispatch 51.5us)
// but VALUBusy 61% / Occupancy 35% -> still part latency-bound: rolling-window
// load_row(c) on the critical path each row-iter, and 24/65 inst/pixel spent
// in the 8-way select-accumulate.
// This round:
//  - quad split: lanes {l, l^16, l^32, l^48} share a cell; 6x6 window (36
//    regs) preloaded ENTIRELY before compute (18 loads, one wait, then pure
//    VALU). 16384 waves = 2 residency fills. Hot code ~8KB.
//  - cascade accumulate: nesting (u>b3)<=(u>W)<=(u>b1) makes contributions
//    {wP-p1, p1-p2, p2-p3, p3} EXACTLY 0-or-wA; sign-split banks
//    accA[c]->bin c, accB[c]->bin 7-c are disjoint. 16 inst/px vs 24.
//    Flagged lanes: w0 = flag?0:mag (exact +0 in cascade), slot-adds done
//    inside the rare branch -- decisions + flagged chain bit-identical to r18.
// Numerics FROZEN from r14 per-pixel (f32 pairwise-9 conv, sector fast path,
// CR-atan2 boundary window, razor hedge). New reassociation: quad-tree cell
// sum (same class as accepted r16 pair split, ~1 ulp).
__global__ __launch_bounds__(256, 4) void hog_kernel(const float* __restrict__ x,
                                                     float* __restrict__ out) {
#pragma clang fp contract(off)
    const int tid  = threadIdx.x;
    const int w    = tid >> 6;          // wave in block 0..3
    const int lane = tid & 63;
    const int cl   = lane & 15;         // cell within wave 0..15
    const int qid  = lane >> 4;         // quad member 0..3
    const int sr   = qid >> 1;          // sub-row block (0: rows 0-3, 1: 4-7)
    const int sc   = qid & 1;           // sub-col block (0: cols 0-3, 1: 4-7)

    const int cx = (w << 4) | cl;       // cell col 0..63
    const int cy = blockIdx.x;          // cell row 0..63
    const int n  = blockIdx.y;          // image 0..63

    const float* img = x + (size_t)n * (IMG_H * IMG_W);
    const int x0 = (cx << 3) + (sc << 2);   // first compute col (mult of 4)
    const int y0 = (cy << 3) + (sr << 2);   // first compute row

    // preload the full 6x6 window: rows y0-1..y0+4, cols x0-1..x0+4
    float r[6][6];
#pragma unroll
    for (int i = 0; i < 6; ++i) {
        const int y = y0 - 1 + i;
        if (y < 0 || y >= IMG_H) {
#pragma unroll
            for (int j = 0; j < 6; ++j) r[i][j] = 0.0f;
        } else {
            const float* row = img + (size_t)y * IMG_W;
            const float4 p = *(const float4*)(row + x0);
            r[i][1] = p.x; r[i][2] = p.y; r[i][3] = p.z; r[i][4] = p.w;
            r[i][0] = (x0 == 0)           ? 0.0f : row[x0 - 1];
            r[i][5] = (x0 + 4 >= IMG_W)   ? 0.0f : row[x0 + 4];
        }
    }

    float accA[4], accB[4], acc8;       // accA[c]=bin c; accB[c]=bin 7-c; acc8=bin 8
#pragma unroll
    for (int k = 0; k < 4; ++k) { accA[k] = 0.0f; accB[k] = 0.0f; }
    acc8 = 0.0f;

    const float PI_F = 3.14159274101257324f;   // float32(pi)
    const float T1F  = 0.41421356237309503f;   // tan(pi/8) -> f32
    const float T3F  = 2.41421356237309503f;   // tan(3pi/8) -> f32
    const float KPI  = 2.54647909f;            // 8/pi
    const float EPS  = 5e-5f;                  // boundary window in t-units

#pragma unroll
    for (int ry = 0; ry < 4; ++ry) {
#pragma unroll
        for (int j = 0; j < 4; ++j) {
            const float A0 = r[ry][j],     A1 = r[ry][j + 1], A2 = r[ry][j + 2];
            const float B0 = r[ry + 1][j],                    B2 = r[ry + 1][j + 2];
            const float C0 = r[ry + 2][j], C1 = r[ry + 2][j + 1], C2 = r[ry + 2][j + 2];

            // numpy pairwise-9 association (one f32 rounding per add):
            const float gx = ((-A0 + (A2 - 2.0f * B0)) + (2.0f * B2 - C0)) + C2;
            const float gy = (((-A0 - 2.0f * A1) + (-A2)) + (C0 + 2.0f * C1)) + C2;

            const float u = fabsf(gx);
            const float W = fabsf(gy);
            const float q = u * u + W * W;
            const float mag = sqrtf(q);

            // sector boundaries u/W in {tan(pi/8), 1, tan(3pi/8)}; nested:
            // c3 => c2 => c1
            const float b1 = W * T1F;
            const float b3 = W * T3F;
            const bool c1 = u > b1;
            const bool c2 = u > W;
            const bool c3 = u > b3;
            const bool s  = gy > 0.0f;

            // boundary window (min form == r14's OR form bit-identically)
            const float KW = KPI * W;
            const float E  = EPS * q;
            const float md = fminf(fminf(fabsf(u - b1), fabsf(u - b3)),
                                   fminf(fabsf(u - W), u));
            const bool flag = md * KW < E;

            // cascade accumulate (exact: every contribution is 0 or wA)
            const float w0 = flag ? 0.0f : mag;
            const float wP = s ? w0 : 0.0f;
            const float wN = w0 - wP;               // exact
            const float p1 = c1 ? wP : 0.0f;
            const float p2 = c2 ? wP : 0.0f;
            const float p3 = c3 ? wP : 0.0f;
            const float n1 = c1 ? wN : 0.0f;
            const float n2 = c2 ? wN : 0.0f;
            const float n3 = c3 ? wN : 0.0f;
            accA[0] += wP - p1; accA[1] += p1 - p2;
            accA[2] += p2 - p3; accA[3] += p3;
            accB[0] += wN - n1; accB[1] += n1 - n2;
            accB[2] += n2 - n3; accB[3] += n3;

            if (flag) {
                // faithful r14 chain: CR f32 atan2 (via f64), CR f32 div
                const float angf = (float)atan2((double)u, (double)gy);
                const float tc = (float)((double)angf / (double)PI_F) * 8.0f;
                int bc = (int)tc;
                int bin = bc > 8 ? 8 : bc;
                float wA = mag;
                const float tn = roundf(tc);
                const int B = (int)tn;
                if (B >= 1 && B <= 8 && fabsf(tc - tn) < 4e-6f &&
                    mag <= 1.05f) {
                    // razor hedge: 50/50 split across {B-1, B}
                    const float hw = 0.5f * mag;
                    // add hw to slot B (select-adds; +0.0f elsewhere, exact)
                    accA[0] += (B == 0) ? hw : 0.0f;
                    accA[1] += (B == 1) ? hw : 0.0f;
                    accA[2] += (B == 2) ? hw : 0.0f;
                    accA[3] += (B == 3) ? hw : 0.0f;
                    accB[3] += (B == 4) ? hw : 0.0f;
                    accB[2] += (B == 5) ? hw : 0.0f;
                    accB[1] += (B == 6) ? hw : 0.0f;
                    accB[0] += (B == 7) ? hw : 0.0f;
                    acc8    += (B == 8) ? hw : 0.0f;
                    bin = B - 1; wA = hw;
                }
                accA[0] += (bin == 0) ? wA : 0.0f;
                accA[1] += (bin == 1) ? wA : 0.0f;
                accA[2] += (bin == 2) ? wA : 0.0f;
                accA[3] += (bin == 3) ? wA : 0.0f;
                accB[3] += (bin == 4) ? wA : 0.0f;
                accB[2] += (bin == 5) ? wA : 0.0f;
                accB[1] += (bin == 6) ? wA : 0.0f;
                accB[0] += (bin == 7) ? wA : 0.0f;
                acc8    += (bin == 8) ? wA : 0.0f;
            }
        }
    }

    // quad reduction: {l, l^16, l^32, l^48} share one cell; 2-round xor tree,
    // all 4 lanes converge to the identical sum (commutative, same shape).
    const float vals[NB] = {accA[0], accA[1], accA[2], accA[3],
                            accB[3], accB[2], accB[1], accB[0], acc8};
    float* o = out + (size_t)n * (NB * 64 * 64) + (size_t)cy * 64 + cx;
#pragma unroll
    for (int k = 0; k < NB; ++k) {
        float v = vals[k];
        v += __shfl_xor(v, 16, 64);
        v += __shfl_xor(v, 32, 64);
        if ((k & 3) == qid) o[(size_t)k * 4096] = v;  // 16 coalesced lanes/bin
    }
}

extern "C" void kernel_launch(void* const* d_in, const int* in_sizes, int n_in,
                              void* d_out, int out_size, void* d_ws, size_t ws_size,
                              hipStream_t stream) {
    const float* x = (const float*)d_in[0];
    float* out = (float*)d_out;
    hog_kernel<<<dim3(64, 64, 1), dim3(256, 1, 1), 0, stream>>>(x, out);
}